// Round 1
// baseline (499.812 us; speedup 1.0000x reference)
//
#include <hip/hip_runtime.h>

// Problem constants: x,y are (16, 64, 256, 256) fp32.
#define NB 16
#define C  64
#define HW 65536          // 256*256
#define HW4 (HW / 4)      // float4 count per row

// ---------------------------------------------------------------------------
// Kernel 1: N_mean[b,c] = (1/HW) * sum_j y[b,c,j]
// One block per (b,c) row (1024 blocks), 256 threads, float4 streaming loads.
// ---------------------------------------------------------------------------
__global__ __launch_bounds__(256) void mean_kernel(const float* __restrict__ y,
                                                   float* __restrict__ wmean) {
    const int row = blockIdx.x;                     // b*64 + c
    const float4* y4 = (const float4*)(y + (size_t)row * HW);
    const int tid = threadIdx.x;

    float4 acc = make_float4(0.f, 0.f, 0.f, 0.f);
    #pragma unroll 8
    for (int k = tid; k < HW4; k += 256) {          // 64 iterations/thread
        float4 v = y4[k];
        acc.x += v.x; acc.y += v.y; acc.z += v.z; acc.w += v.w;
    }
    float s = (acc.x + acc.y) + (acc.z + acc.w);

    // wave-64 shuffle reduce
    #pragma unroll
    for (int off = 32; off > 0; off >>= 1)
        s += __shfl_down(s, off, 64);

    __shared__ float smem[4];
    const int lane = tid & 63, wv = tid >> 6;
    if (lane == 0) smem[wv] = s;
    __syncthreads();
    if (tid == 0) {
        float t = (smem[0] + smem[1]) + (smem[2] + smem[3]);
        wmean[row] = t * (1.0f / HW);               // 2^-16: exact
    }
}

// ---------------------------------------------------------------------------
// Kernel 2: out[b,i] = (1/(HW*C)) * sum_c x[b,c,i] * wmean[b,c]
// One float4 of output per thread; 64 coalesced float4 loads down the c axis.
// 1024 blocks (16 b * 64 column-chunks) x 256 threads.
// ---------------------------------------------------------------------------
__global__ __launch_bounds__(256) void gemv_kernel(const float* __restrict__ x,
                                                   const float* __restrict__ wmean,
                                                   float* __restrict__ out) {
    const int b  = blockIdx.x >> 6;                       // 64 blocks per batch
    const int i4 = ((blockIdx.x & 63) << 8) + threadIdx.x; // float4 idx in [0,16384)

    __shared__ float ws[C];
    if (threadIdx.x < C) ws[threadIdx.x] = wmean[(b << 6) + threadIdx.x];
    __syncthreads();

    const float4* x4 = (const float4*)x + (size_t)b * (C * (size_t)HW4) + i4;

    float4 acc = make_float4(0.f, 0.f, 0.f, 0.f);
    #pragma unroll
    for (int d = 0; d < C; ++d) {
        float4 v = x4[(size_t)d * HW4];
        const float wd = ws[d];
        acc.x += v.x * wd; acc.y += v.y * wd;
        acc.z += v.z * wd; acc.w += v.w * wd;
    }

    const float scale = 1.0f / (float)(HW * C);           // 2^-22: exact
    acc.x *= scale; acc.y *= scale; acc.z *= scale; acc.w *= scale;

    ((float4*)out)[(size_t)b * HW4 + i4] = acc;
}

extern "C" void kernel_launch(void* const* d_in, const int* in_sizes, int n_in,
                              void* d_out, int out_size, void* d_ws, size_t ws_size,
                              hipStream_t stream) {
    const float* x = (const float*)d_in[0];
    const float* y = (const float*)d_in[1];
    float* out = (float*)d_out;
    float* wmean = (float*)d_ws;   // 1024 floats = 4 KiB scratch

    mean_kernel<<<dim3(NB * C), dim3(256), 0, stream>>>(y, wmean);
    gemv_kernel<<<dim3(NB * C), dim3(256), 0, stream>>>(x, wmean, out);
}

// Round 2
// 499.350 us; speedup vs baseline: 1.0009x; 1.0009x over previous
//
#include <hip/hip_runtime.h>

// Problem constants: x,y are (16, 64, 256, 256) fp32.
#define NB 16
#define C  64
#define HW 65536          // 256*256
#define HW4 (HW / 4)      // float4 count per row

// ---------------------------------------------------------------------------
// Kernel 1: wmean[b,c] = sum_j y[b,c,j] * (1/HW) * (1/(HW*C))
// Both scales are exact powers of two (2^-16, 2^-22) -> folding is bit-exact.
// One block per (b,c) row (1024 blocks), 256 threads, float4 streaming loads.
// ---------------------------------------------------------------------------
__global__ __launch_bounds__(256) void mean_kernel(const float* __restrict__ y,
                                                   float* __restrict__ wmean) {
    const int row = blockIdx.x;                     // b*64 + c
    const float4* y4 = (const float4*)(y + (size_t)row * HW);
    const int tid = threadIdx.x;

    float4 acc = make_float4(0.f, 0.f, 0.f, 0.f);
    #pragma unroll 8
    for (int k = tid; k < HW4; k += 256) {          // 64 iterations/thread
        float4 v = y4[k];
        acc.x += v.x; acc.y += v.y; acc.z += v.z; acc.w += v.w;
    }
    float s = (acc.x + acc.y) + (acc.z + acc.w);

    // wave-64 shuffle reduce
    #pragma unroll
    for (int off = 32; off > 0; off >>= 1)
        s += __shfl_down(s, off, 64);

    __shared__ float smem[4];
    const int lane = tid & 63, wv = tid >> 6;
    if (lane == 0) smem[wv] = s;
    __syncthreads();
    if (tid == 0) {
        float t = (smem[0] + smem[1]) + (smem[2] + smem[3]);
        // fold mean (2^-16) AND final scale (2^-22): both exact pow2
        wmean[row] = t * (1.0f / HW) * (1.0f / ((float)HW * (float)C));
    }
}

// ---------------------------------------------------------------------------
// Kernel 2: out[b,i] = sum_c x[b,c,i] * wmean[b,c]   (scale pre-folded)
// One float4 of output per thread; 64 coalesced float4 loads down the c axis.
// 1024 blocks (16 b * 64 column-chunks) x 256 threads.
// unroll 16 keeps load-data VGPRs at ~64; launch_bounds(256,4) caps VGPR<=128
// so all 4 blocks/CU stay resident (16 waves/CU latency hiding).
// ---------------------------------------------------------------------------
__global__ __launch_bounds__(256, 4) void gemv_kernel(const float* __restrict__ x,
                                                      const float* __restrict__ wmean,
                                                      float* __restrict__ out) {
    const int b  = blockIdx.x >> 6;                        // 64 blocks per batch
    const int i4 = ((blockIdx.x & 63) << 8) + threadIdx.x; // float4 idx in [0,16384)

    __shared__ float ws[C];
    if (threadIdx.x < C) ws[threadIdx.x] = wmean[(b << 6) + threadIdx.x];
    __syncthreads();

    const float4* x4 = (const float4*)x + (size_t)b * (C * (size_t)HW4) + i4;

    float4 acc = make_float4(0.f, 0.f, 0.f, 0.f);
    #pragma unroll 16
    for (int d = 0; d < C; ++d) {
        float4 v = x4[(size_t)d * HW4];
        const float wd = ws[d];
        acc.x += v.x * wd; acc.y += v.y * wd;
        acc.z += v.z * wd; acc.w += v.w * wd;
    }

    ((float4*)out)[(size_t)b * HW4 + i4] = acc;
}

extern "C" void kernel_launch(void* const* d_in, const int* in_sizes, int n_in,
                              void* d_out, int out_size, void* d_ws, size_t ws_size,
                              hipStream_t stream) {
    const float* x = (const float*)d_in[0];
    const float* y = (const float*)d_in[1];
    float* out = (float*)d_out;
    float* wmean = (float*)d_ws;   // 1024 floats = 4 KiB scratch

    mean_kernel<<<dim3(NB * C), dim3(256), 0, stream>>>(y, wmean);
    gemv_kernel<<<dim3(NB * C), dim3(256), 0, stream>>>(x, wmean, out);
}